// Round 6
// baseline (418.573 us; speedup 1.0000x reference)
//
#include <hip/hip_runtime.h>

#define NNODES 50000
#define NEDGES 200000
#define NSCANB ((NNODES + 255) / 256)   // 196 scan blocks

typedef short  bf16x8 __attribute__((ext_vector_type(8)));
typedef float  f32x4  __attribute__((ext_vector_type(4)));
typedef unsigned int u32x4 __attribute__((ext_vector_type(4)));

__device__ __forceinline__ unsigned short f2bf(float f) {
    union { float f; unsigned int u; } c; c.f = f;
    unsigned int r = c.u + 0x7fffu + ((c.u >> 16) & 1u);
    return (unsigned short)(r >> 16);
}
__device__ __forceinline__ float bf2f(unsigned short h) {
    union { unsigned int u; float f; } c; c.u = ((unsigned int)h) << 16;
    return c.f;
}
__device__ __forceinline__ float bflo(unsigned int v) {
    union { unsigned int u; float f; } c; c.u = v << 16;
    return c.f;
}
__device__ __forceinline__ float bfhi(unsigned int v) {
    union { unsigned int u; float f; } c; c.u = v & 0xffff0000u;
    return c.f;
}

// ---------------- fused prep: deg=0, Bt1, Bt2, x->bf16 + UW=(v*e^v, e^v) ----
#define PREP_Z NNODES                 // zero deg
#define PREP_B1 (256 * 1024)          // Bt1 elements
#define PREP_B2 (64 * 512)            // Bt2 elements
#define PREP_XC (NNODES * 64)         // x chunks (8 features each)
#define PREP_TOT (PREP_Z + PREP_B1 + PREP_B2 + PREP_XC)
__global__ __launch_bounds__(256) void k_prep(const float* __restrict__ x,
                                              const float* __restrict__ W1_rel,
                                              const float* __restrict__ W1_root,
                                              const float* __restrict__ W2_rel,
                                              const float* __restrict__ W2_root,
                                              int* __restrict__ deg,
                                              unsigned short* __restrict__ Bt1,
                                              unsigned short* __restrict__ Bt2,
                                              unsigned short* __restrict__ xb,
                                              uint2* __restrict__ UW) {
    int i = blockIdx.x * 256 + threadIdx.x;
    if (i < PREP_Z) { deg[i] = 0; return; }
    i -= PREP_Z;
    if (i < PREP_B1) {
        int n = i >> 10, k = i & 1023;
        float v = (k < 512) ? W1_rel[k * 256 + n] : W1_root[(k - 512) * 256 + n];
        Bt1[i] = f2bf(v);
        return;
    }
    i -= PREP_B1;
    if (i < PREP_B2) {
        int n = i >> 9, k = i & 511;
        float v = (k < 256) ? W2_rel[k * 64 + n] : W2_root[(k - 256) * 64 + n];
        Bt2[i] = f2bf(v);
        return;
    }
    i -= PREP_B2;
    if (i < PREP_XC) {
        int n = i >> 6, c8 = (i & 63) * 8;
        const float* xp = x + (size_t)n * 512 + c8;
        float4 a = *(const float4*)xp;
        float4 b = *(const float4*)(xp + 4);
        float v[8] = {a.x, a.y, a.z, a.w, b.x, b.y, b.z, b.w};
        unsigned short o[8];
        uint2 uw[4];
#pragma unroll
        for (int j = 0; j < 8; ++j) o[j] = f2bf(v[j]);
#pragma unroll
        for (int p = 0; p < 4; ++p) {
            float v0 = v[2 * p], v1 = v[2 * p + 1];
            float e0 = __expf(v0), e1 = __expf(v1);
            uw[p].x = (unsigned int)f2bf(v0 * e0) | ((unsigned int)f2bf(v1 * e1) << 16);
            uw[p].y = (unsigned int)f2bf(e0) | ((unsigned int)f2bf(e1) << 16);
        }
        *(u32x4*)(xb + (size_t)n * 512 + c8) = *(const u32x4*)o;
        uint2* uwp = UW + (size_t)n * 256 + (c8 >> 1);
        *(u32x4*)uwp = *(const u32x4*)&uw[0];
        *(u32x4*)(uwp + 2) = *(const u32x4*)&uw[2];
    }
}

// ---------------- CSR build ----------------
__global__ void k_count(const int* __restrict__ ei, int* __restrict__ deg) {
    int e = blockIdx.x * 256 + threadIdx.x;
    if (e < NEDGES) atomicAdd(&deg[ei[NEDGES + e]], 1);
}

__global__ __launch_bounds__(256) void k_scanA(const int* __restrict__ deg,
                                               int* __restrict__ rs,
                                               int* __restrict__ partials) {
    __shared__ int sm[256];
    int t = threadIdx.x, i = blockIdx.x * 256 + t;
    int v = (i < NNODES) ? deg[i] : 0;
    sm[t] = v;
    __syncthreads();
#pragma unroll
    for (int off = 1; off < 256; off <<= 1) {
        int u = (t >= off) ? sm[t - off] : 0;
        __syncthreads();
        sm[t] += u;
        __syncthreads();
    }
    if (i < NNODES) rs[i] = sm[t] - v;
    if (t == 255) partials[blockIdx.x] = sm[255];
}

__global__ __launch_bounds__(256) void k_scanB(int* __restrict__ partials) {
    __shared__ int sm[256];
    int t = threadIdx.x;
    int v = (t < NSCANB) ? partials[t] : 0;
    sm[t] = v;
    __syncthreads();
#pragma unroll
    for (int off = 1; off < 256; off <<= 1) {
        int u = (t >= off) ? sm[t - off] : 0;
        __syncthreads();
        sm[t] += u;
        __syncthreads();
    }
    if (t < NSCANB) partials[t] = sm[t] - v;
}

__global__ __launch_bounds__(256) void k_scanC(int* __restrict__ rs,
                                               const int* __restrict__ partials,
                                               int* __restrict__ cursor) {
    int t = threadIdx.x, b = blockIdx.x, i = b * 256 + t;
    if (i < NNODES) {
        int v = rs[i] + partials[b];
        rs[i] = v;
        cursor[i] = v;
    }
    if (i == 0) rs[NNODES] = NEDGES;
}

__global__ void k_scatter(const int* __restrict__ ei, int* __restrict__ cursor,
                          int* __restrict__ srcs) {
    int e = blockIdx.x * 256 + threadIdx.x;
    if (e < NEDGES) {
        int d = ei[NEDGES + e];
        int p = atomicAdd(&cursor[d], 1);
        srcs[p] = ei[e];
    }
}

// ---------------- softmax aggregation (layer 1): pure gather-accumulate -----
// block = one dst node; thread t handles features 2t,2t+1 via one uint2 load
// of precomputed (u=v*e^v, w=e^v). out = sum(u)/sum(w).
__global__ __launch_bounds__(256) void k_agg1(const uint2* __restrict__ UW,
                                              const int* __restrict__ rs,
                                              const int* __restrict__ srcs,
                                              unsigned short* __restrict__ AggBuf) {
    int n = blockIdx.x;
    int t = threadIdx.x;
    int e0 = rs[n], e1 = rs[n + 1];
    float nu0 = 0.f, nu1 = 0.f, de0 = 0.f, de1 = 0.f;
    for (int e = e0; e < e1; ++e) {
        int s = srcs[e];
        uint2 vw = UW[(size_t)s * 256 + t];
        nu0 += bflo(vw.x); nu1 += bfhi(vw.x);
        de0 += bflo(vw.y); de1 += bfhi(vw.y);
    }
    float a0 = nu0 / fmaxf(de0, 1e-16f);
    float a1 = nu1 / fmaxf(de1, 1e-16f);
    unsigned int o = (unsigned int)f2bf(a0) | ((unsigned int)f2bf(a1) << 16);
    *(unsigned int*)(AggBuf + (size_t)n * 512 + t * 2) = o;
}

// ---------------- sum aggregation (layer 2): 2 nodes per block ----------------
__global__ __launch_bounds__(256) void k_agg2(const int* __restrict__ rs,
                                              const int* __restrict__ srcs,
                                              const unsigned short* __restrict__ H1,
                                              unsigned short* __restrict__ Seg) {
    int half = threadIdx.x >> 7;
    int t = threadIdx.x & 127;
    int n = blockIdx.x * 2 + half;
    int e0 = rs[n], e1 = rs[n + 1];
    float a0 = 0.f, a1 = 0.f;
    for (int e = e0; e < e1; ++e) {
        int s = srcs[e];
        unsigned int v = *(const unsigned int*)(H1 + (size_t)s * 256 + t * 2);
        a0 += bf2f((unsigned short)(v & 0xffffu));
        a1 += bf2f((unsigned short)(v >> 16));
    }
    unsigned int o = (unsigned int)f2bf(a0) | ((unsigned int)f2bf(a1) << 16);
    *(unsigned int*)(Seg + (size_t)n * 256 + t * 2) = o;
}

// ---------------- GEMM1: 64x128 tile, split-A [AggBuf|xb], -> H1 bf16 -------
// Epilogue computes the per-row index-softmax (aggidx) in-block from CSR.
__global__ __launch_bounds__(256, 5) void k_gemm1(const unsigned short* __restrict__ A1,
                                                  const unsigned short* __restrict__ A2,
                                                  const unsigned short* __restrict__ Bt,
                                                  const int* __restrict__ rs,
                                                  const int* __restrict__ srcs,
                                                  const float* __restrict__ r1,
                                                  const float* __restrict__ r2,
                                                  const float* __restrict__ bias,
                                                  unsigned short* __restrict__ outp) {
    constexpr int BM = 64, BN = 128, BK = 64;
    __shared__ __align__(16) unsigned short As[BM * BK];
    __shared__ __align__(16) unsigned short Bs[BN * BK];
    __shared__ float s1t[BM];

    const int tid = threadIdx.x;
    const int w = tid >> 6;
    const int lane = tid & 63;
    const int lm = lane & 15;
    const int quad = lane >> 4;
    const int wr = w >> 1;
    const int wc = w & 1;
    const int rowbase = blockIdx.y * BM;
    const int colbase = blockIdx.x * BN;
    const int wrow = wr * 32;
    const int wcol = wc * 64;

    const int rsub = lane >> 3;
    const int csw = (lane & 7) ^ rsub;

    f32x4 acc[2][4];
#pragma unroll
    for (int mi = 0; mi < 2; ++mi)
#pragma unroll
        for (int ni = 0; ni < 4; ++ni) acc[mi][ni] = (f32x4){0.f, 0.f, 0.f, 0.f};

    for (int kt = 0; kt < 1024; kt += BK) {
        const unsigned short* Ab = (kt < 512) ? A1 : A2;
        int kof = (kt < 512) ? kt : kt - 512;
#pragma unroll
        for (int l = 0; l < 2; ++l) {
            int r = w * 16 + l * 8;
            int gr = rowbase + r + rsub;
            if (gr >= NNODES) gr = NNODES - 1;
            const unsigned short* gp = Ab + (size_t)gr * 512 + kof + csw * 8;
            __builtin_amdgcn_global_load_lds(
                (const __attribute__((address_space(1))) void*)gp,
                (__attribute__((address_space(3))) void*)(As + r * BK), 16, 0, 0);
        }
#pragma unroll
        for (int l = 0; l < 4; ++l) {
            int r = w * 32 + l * 8;
            const unsigned short* gp = Bt + (size_t)(colbase + r + rsub) * 1024 + kt + csw * 8;
            __builtin_amdgcn_global_load_lds(
                (const __attribute__((address_space(1))) void*)gp,
                (__attribute__((address_space(3))) void*)(Bs + r * BK), 16, 0, 0);
        }
        __syncthreads();
#pragma unroll
        for (int kk = 0; kk < BK; kk += 32) {
            const int kidx = (kk >> 3) + quad;
            const int phys = kidx ^ (lm & 7);
            bf16x8 af[2], bfr[4];
#pragma unroll
            for (int mi = 0; mi < 2; ++mi)
                af[mi] = __builtin_bit_cast(bf16x8,
                    *(const u32x4*)(As + (wrow + mi * 16 + lm) * BK + phys * 8));
#pragma unroll
            for (int ni = 0; ni < 4; ++ni)
                bfr[ni] = __builtin_bit_cast(bf16x8,
                    *(const u32x4*)(Bs + (wcol + ni * 16 + lm) * BK + phys * 8));
#pragma unroll
            for (int mi = 0; mi < 2; ++mi)
#pragma unroll
                for (int ni = 0; ni < 4; ++ni)
                    acc[mi][ni] = __builtin_amdgcn_mfma_f32_16x16x32_bf16(
                        af[mi], bfr[ni], acc[mi][ni], 0, 0, 0);
        }
        __syncthreads();
    }

    // per-row index softmax (max-shifted: values up to 5e4)
    if (tid < BM) {
        int grow = rowbase + tid;
        float r_ = 0.f;
        if (grow < NNODES) {
            int e0 = rs[grow], e1 = rs[grow + 1];
            float m = -INFINITY, d = 0.f, q = 0.f;
            for (int e = e0; e < e1; ++e) {
                float v = (float)srcs[e];
                float nm = fmaxf(m, v);
                float sc = __expf(m - nm), ee = __expf(v - nm);
                d = d * sc + ee;
                q = q * sc + ee * v;
                m = nm;
            }
            r_ = q / fmaxf(d, 1e-16f);
        }
        s1t[tid] = r_;
    }
    __syncthreads();

#pragma unroll
    for (int ni = 0; ni < 4; ++ni) {
        int gc = colbase + wcol + ni * 16 + lm;
        float r1v = r1[gc], r2v = r2[gc], bv = bias[gc];
#pragma unroll
        for (int mi = 0; mi < 2; ++mi) {
#pragma unroll
            for (int r = 0; r < 4; ++r) {
                int lrow = wrow + mi * 16 + quad * 4 + r;
                int grow = rowbase + lrow;
                if (grow < NNODES) {
                    float v = acc[mi][ni][r] + s1t[lrow] * r1v + (float)grow * r2v + bv;
                    v = (v >= 0.f) ? v : 0.01f * v;
                    outp[(size_t)grow * 256 + gc] = f2bf(v);
                }
            }
        }
    }
}

// ---------------- GEMM2 + fused head: 64x64 tile, split-A [Seg|H1] ----------
// Epilogue computes per-row index-sum (sidx) in-block from CSR, then the head.
__global__ __launch_bounds__(256) void k_gemm2h(const unsigned short* __restrict__ A1,
                                                const unsigned short* __restrict__ A2,
                                                const unsigned short* __restrict__ Bt,
                                                const int* __restrict__ rs,
                                                const int* __restrict__ srcs,
                                                const float* __restrict__ r1,
                                                const float* __restrict__ r2,
                                                const float* __restrict__ bias,
                                                const float* __restrict__ Wp,
                                                const float* __restrict__ bp,
                                                const float* __restrict__ Wr,
                                                const float* __restrict__ br,
                                                float* __restrict__ out) {
    constexpr int BM = 64, BN = 64, BK = 64;
    __shared__ __align__(16) unsigned short As[BM * BK];
    __shared__ __align__(16) unsigned short Bs[BN * BK];
    __shared__ float h2t[BM * 65];
    __shared__ float s1t[BM];

    const int tid = threadIdx.x;
    const int w = tid >> 6;
    const int lane = tid & 63;
    const int lm = lane & 15;
    const int quad = lane >> 4;
    const int rowbase = blockIdx.x * BM;
    const int wrow = w * 16;

    const int rsub = lane >> 3;
    const int csw = (lane & 7) ^ rsub;

    f32x4 acc[4];
#pragma unroll
    for (int ni = 0; ni < 4; ++ni) acc[ni] = (f32x4){0.f, 0.f, 0.f, 0.f};

    for (int kt = 0; kt < 512; kt += BK) {
        const unsigned short* Ab = (kt < 256) ? A1 : A2;
        int kof = (kt < 256) ? kt : kt - 256;
#pragma unroll
        for (int l = 0; l < 2; ++l) {
            int r = w * 16 + l * 8;
            int gr = rowbase + r + rsub;
            if (gr >= NNODES) gr = NNODES - 1;
            const unsigned short* gp = Ab + (size_t)gr * 256 + kof + csw * 8;
            __builtin_amdgcn_global_load_lds(
                (const __attribute__((address_space(1))) void*)gp,
                (__attribute__((address_space(3))) void*)(As + r * BK), 16, 0, 0);
        }
#pragma unroll
        for (int l = 0; l < 2; ++l) {
            int r = w * 16 + l * 8;
            const unsigned short* gp = Bt + (size_t)(r + rsub) * 512 + kt + csw * 8;
            __builtin_amdgcn_global_load_lds(
                (const __attribute__((address_space(1))) void*)gp,
                (__attribute__((address_space(3))) void*)(Bs + r * BK), 16, 0, 0);
        }
        __syncthreads();
#pragma unroll
        for (int kk = 0; kk < BK; kk += 32) {
            const int kidx = (kk >> 3) + quad;
            const int phys = kidx ^ (lm & 7);
            bf16x8 af;
            af = __builtin_bit_cast(bf16x8,
                *(const u32x4*)(As + (wrow + lm) * BK + phys * 8));
            bf16x8 bfr[4];
#pragma unroll
            for (int ni = 0; ni < 4; ++ni)
                bfr[ni] = __builtin_bit_cast(bf16x8,
                    *(const u32x4*)(Bs + (ni * 16 + lm) * BK + phys * 8));
#pragma unroll
            for (int ni = 0; ni < 4; ++ni)
                acc[ni] = __builtin_amdgcn_mfma_f32_16x16x32_bf16(
                    af, bfr[ni], acc[ni], 0, 0, 0);
        }
        __syncthreads();
    }

    // per-row index sum
    if (tid < BM) {
        int grow = rowbase + tid;
        float si = 0.f;
        if (grow < NNODES) {
            int e0 = rs[grow], e1 = rs[grow + 1];
            for (int e = e0; e < e1; ++e) si += (float)srcs[e];
        }
        s1t[tid] = si;
    }
    __syncthreads();

    // epilogue -> LDS h2 tile
#pragma unroll
    for (int ni = 0; ni < 4; ++ni) {
        int gc = ni * 16 + lm;
        float r1v = r1[gc], r2v = r2[gc], bv = bias[gc];
#pragma unroll
        for (int r = 0; r < 4; ++r) {
            int lrow = wrow + quad * 4 + r;
            int grow = rowbase + lrow;
            float v = acc[ni][r] + s1t[lrow] * r1v + (float)grow * r2v + bv;
            v = (v >= 0.f) ? v : 0.01f * v;
            h2t[lrow * 65 + gc] = v;
        }
    }
    __syncthreads();

    // head: threads 0..63, one row each
    if (tid < BM) {
        int grow = rowbase + tid;
        if (grow < NNODES) {
            const float* hv = h2t + tid * 65;
            float idx = (float)grow;
            float p0 = 0.f, p1 = 0.f, p2 = 0.f;
            float r0 = 0.f, r1a = 0.f, r2a = 0.f, r3 = 0.f;
#pragma unroll 8
            for (int c = 0; c < 64; ++c) {
                float v = hv[c];
                p0 += v * Wp[c * 3 + 0];
                p1 += v * Wp[c * 3 + 1];
                p2 += v * Wp[c * 3 + 2];
                r0 += v * Wr[c * 4 + 0];
                r1a += v * Wr[c * 4 + 1];
                r2a += v * Wr[c * 4 + 2];
                r3 += v * Wr[c * 4 + 3];
            }
            p0 += idx * Wp[64 * 3 + 0] + bp[0];
            p1 += idx * Wp[64 * 3 + 1] + bp[1];
            p2 += idx * Wp[64 * 3 + 2] + bp[2];
            r0 += idx * Wr[64 * 4 + 0] + br[0];
            r1a += idx * Wr[64 * 4 + 1] + br[1];
            r2a += idx * Wr[64 * 4 + 2] + br[2];
            r3 += idx * Wr[64 * 4 + 3] + br[3];
            float nrm = fmaxf(sqrtf(r0 * r0 + r1a * r1a + r2a * r2a + r3 * r3), 1e-12f);
            float* op = out + (size_t)grow * 7;
            op[0] = p0; op[1] = p1; op[2] = p2;
            op[3] = r0 / nrm; op[4] = r1a / nrm; op[5] = r2a / nrm; op[6] = r3 / nrm;
        }
    }
}

extern "C" void kernel_launch(void* const* d_in, const int* in_sizes, int n_in,
                              void* d_out, int out_size, void* d_ws, size_t ws_size,
                              hipStream_t stream) {
    const float* x       = (const float*)d_in[0];
    const float* W1_rel  = (const float*)d_in[1];
    const float* b1      = (const float*)d_in[2];
    const float* W1_root = (const float*)d_in[3];
    const float* W2_rel  = (const float*)d_in[4];
    const float* b2      = (const float*)d_in[5];
    const float* W2_root = (const float*)d_in[6];
    const float* Wp      = (const float*)d_in[7];
    const float* bp      = (const float*)d_in[8];
    const float* Wr      = (const float*)d_in[9];
    const float* br      = (const float*)d_in[10];
    const int*   ei      = (const int*)d_in[11];
    float* out = (float*)d_out;

    char* ws = (char*)d_ws;
    size_t off = 0;
    auto alloc = [&](size_t bytes) {
        size_t o = off;
        off = (off + bytes + 255) & ~(size_t)255;
        return (void*)(ws + o);
    };
    int*   deg       = (int*)alloc(NNODES * 4);
    int*   cursor    = (int*)alloc(NNODES * 4);
    int*   row_start = (int*)alloc((NNODES + 1) * 4);
    int*   srcs      = (int*)alloc(NEDGES * 4);
    int*   partials  = (int*)alloc(NSCANB * 4);
    unsigned short* xb     = (unsigned short*)alloc((size_t)NNODES * 512 * 2);
    uint2* UW              = (uint2*)alloc((size_t)NNODES * 256 * 8);
    unsigned short* AggBuf = (unsigned short*)alloc((size_t)NNODES * 512 * 2);
    unsigned short* H1     = (unsigned short*)alloc((size_t)NNODES * 256 * 2);
    unsigned short* Seg    = (unsigned short*)alloc((size_t)NNODES * 256 * 2);
    unsigned short* Bt1    = (unsigned short*)alloc(256 * 1024 * 2);
    unsigned short* Bt2    = (unsigned short*)alloc(64 * 512 * 2);

    const int EB = (NEDGES + 255) / 256;

    k_prep<<<(PREP_TOT + 255) / 256, 256, 0, stream>>>(
        x, W1_rel, W1_root, W2_rel, W2_root, deg, Bt1, Bt2, xb, UW);

    k_count<<<EB, 256, 0, stream>>>(ei, deg);
    k_scanA<<<NSCANB, 256, 0, stream>>>(deg, row_start, partials);
    k_scanB<<<1, 256, 0, stream>>>(partials);
    k_scanC<<<NSCANB, 256, 0, stream>>>(row_start, partials, cursor);
    k_scatter<<<EB, 256, 0, stream>>>(ei, cursor, srcs);

    k_agg1<<<NNODES, 256, 0, stream>>>(UW, row_start, srcs, AggBuf);

    // GEMM1: [AggBuf | xb] @ Bt1^T -> H1 (bf16, stride 256). grid (col, row)
    k_gemm1<<<dim3(2, (NNODES + 63) / 64), 256, 0, stream>>>(
        AggBuf, xb, Bt1, row_start, srcs, W1_rel + 512 * 256, W1_root + 512 * 256, b1, H1);

    k_agg2<<<NNODES / 2, 256, 0, stream>>>(row_start, srcs, H1, Seg);

    // GEMM2 + head: [Seg | H1] @ Bt2^T -> out
    k_gemm2h<<<(NNODES + 63) / 64, 256, 0, stream>>>(
        Seg, H1, Bt2, row_start, srcs, W2_rel + 256 * 64, W2_root + 256 * 64, b2,
        Wp, bp, Wr, br, out);
}

// Round 7
// 413.539 us; speedup vs baseline: 1.0122x; 1.0122x over previous
//
#include <hip/hip_runtime.h>

#define NNODES 50000
#define NEDGES 200000
#define CSRB 256                        // blocks in the fused CSR/prep kernel
#define CHUNK 196                       // ceil(NNODES/CSRB)

typedef short  bf16x8 __attribute__((ext_vector_type(8)));
typedef float  f32x4  __attribute__((ext_vector_type(4)));
typedef unsigned int u32x4 __attribute__((ext_vector_type(4)));

__device__ __forceinline__ unsigned short f2bf(float f) {
    union { float f; unsigned int u; } c; c.f = f;
    unsigned int r = c.u + 0x7fffu + ((c.u >> 16) & 1u);
    return (unsigned short)(r >> 16);
}
__device__ __forceinline__ float bf2f(unsigned short h) {
    union { unsigned int u; float f; } c; c.u = ((unsigned int)h) << 16;
    return c.f;
}
__device__ __forceinline__ float bflo(unsigned int v) {
    union { unsigned int u; float f; } c; c.u = v << 16;
    return c.f;
}
__device__ __forceinline__ float bfhi(unsigned int v) {
    union { unsigned int u; float f; } c; c.u = v & 0xffff0000u;
    return c.f;
}

// device-scope grid barrier: all CSRB blocks co-resident (256 blocks / 256 CUs)
__device__ __forceinline__ void gridbar(int* bar, int target) {
    __syncthreads();
    if (threadIdx.x == 0) {
        __hip_atomic_fetch_add(bar, 1, __ATOMIC_ACQ_REL, __HIP_MEMORY_SCOPE_AGENT);
        while (__hip_atomic_load(bar, __ATOMIC_ACQUIRE, __HIP_MEMORY_SCOPE_AGENT) < target)
            __builtin_amdgcn_s_sleep(2);
    }
    __syncthreads();
}

// ---------------- fused: prep (Bt1,Bt2,xcast) + CSR build (count,scan,scatter)
#define PREP_B1 (256 * 1024)
#define PREP_B2 (64 * 512)
#define PREP_XC (NNODES * 64)
__global__ __launch_bounds__(256) void k_csrprep(const float* __restrict__ x,
                                                 const float* __restrict__ W1_rel,
                                                 const float* __restrict__ W1_root,
                                                 const float* __restrict__ W2_rel,
                                                 const float* __restrict__ W2_root,
                                                 const int* __restrict__ ei,
                                                 int* __restrict__ deg,
                                                 int* __restrict__ rs,
                                                 int* __restrict__ cursor,
                                                 int* __restrict__ srcs,
                                                 unsigned short* __restrict__ Bt1,
                                                 unsigned short* __restrict__ Bt2,
                                                 unsigned short* __restrict__ xb,
                                                 int* __restrict__ bar,
                                                 int* __restrict__ blocksum) {
    const int b = blockIdx.x, t = threadIdx.x;
    const int gtid = b * 256 + t;
    const int GS = CSRB * 256;  // 65536

    // ---- phase 0: zero deg + weight transposes + x->bf16 cast ----
    for (int i = gtid; i < NNODES; i += GS) deg[i] = 0;
    for (int i = gtid; i < PREP_B1; i += GS) {
        int n = i >> 10, k = i & 1023;
        float v = (k < 512) ? W1_rel[k * 256 + n] : W1_root[(k - 512) * 256 + n];
        Bt1[i] = f2bf(v);
    }
    for (int i = gtid; i < PREP_B2; i += GS) {
        int n = i >> 9, k = i & 511;
        float v = (k < 256) ? W2_rel[k * 64 + n] : W2_root[(k - 256) * 64 + n];
        Bt2[i] = f2bf(v);
    }
    for (int i = gtid; i < PREP_XC; i += GS) {
        int n = i >> 6, c8 = (i & 63) * 8;
        const float* xp = x + (size_t)n * 512 + c8;
        float4 a = *(const float4*)xp;
        float4 bb = *(const float4*)(xp + 4);
        unsigned short o[8];
        o[0] = f2bf(a.x); o[1] = f2bf(a.y); o[2] = f2bf(a.z); o[3] = f2bf(a.w);
        o[4] = f2bf(bb.x); o[5] = f2bf(bb.y); o[6] = f2bf(bb.z); o[7] = f2bf(bb.w);
        *(u32x4*)(xb + (size_t)n * 512 + c8) = *(const u32x4*)o;
    }
    gridbar(bar, CSRB);

    // ---- phase 1: count ----
    for (int e = gtid; e < NEDGES; e += GS) atomicAdd(&deg[ei[NEDGES + e]], 1);
    gridbar(bar, 2 * CSRB);

    // ---- phase 2a: block-local scan of this block's CHUNK nodes ----
    __shared__ int sm[256];
    int base = b * CHUNK;
    int idx = base + t;
    int v = 0;
    if (t < CHUNK && idx < NNODES) v = deg[idx];
    sm[t] = v;
    __syncthreads();
#pragma unroll
    for (int off = 1; off < 256; off <<= 1) {
        int u = (t >= off) ? sm[t - off] : 0;
        __syncthreads();
        sm[t] += u;
        __syncthreads();
    }
    int excl = sm[t] - v;           // block-local exclusive prefix
    if (t == 255) blocksum[b] = sm[255];
    gridbar(bar, 3 * CSRB);

    // ---- phase 2b: global offsets, write rs + cursor ----
    __shared__ int sb[256];
    sb[t] = blocksum[t];
    __syncthreads();
#pragma unroll
    for (int off = 1; off < 256; off <<= 1) {
        int u = (t >= off) ? sb[t - off] : 0;
        __syncthreads();
        sb[t] += u;
        __syncthreads();
    }
    int off0 = (b == 0) ? 0 : sb[b - 1];
    if (t < CHUNK && idx < NNODES) {
        int rv = off0 + excl;
        rs[idx] = rv;
        cursor[idx] = rv;
    }
    if (b == 0 && t == 0) rs[NNODES] = NEDGES;
    gridbar(bar, 4 * CSRB);

    // ---- phase 3: scatter ----
    for (int e = gtid; e < NEDGES; e += GS) {
        int d = ei[NEDGES + e];
        int p = atomicAdd(&cursor[d], 1);
        srcs[p] = ei[e];
    }
}

// ---------------- softmax aggregation (layer 1): wave-per-node -------------
// 4 nodes/block; lane handles 8 features via one b128 load per edge.
// No max-subtraction: |x| < ~6, exp() safe in f32.
__global__ __launch_bounds__(256) void k_agg1(const unsigned short* __restrict__ xb,
                                              const int* __restrict__ rs,
                                              const int* __restrict__ srcs,
                                              unsigned short* __restrict__ AggBuf) {
    int wv = threadIdx.x >> 6;
    int lane = threadIdx.x & 63;
    int n = blockIdx.x * 4 + wv;
    int e0 = rs[n], e1 = rs[n + 1];
    float nu[8], de[8];
#pragma unroll
    for (int j = 0; j < 8; ++j) { nu[j] = 0.f; de[j] = 0.f; }
    int e = e0;
    for (; e + 1 < e1; e += 2) {
        int s0 = srcs[e], s1 = srcs[e + 1];
        u32x4 r0 = *(const u32x4*)(xb + (size_t)s0 * 512 + lane * 8);
        u32x4 r1 = *(const u32x4*)(xb + (size_t)s1 * 512 + lane * 8);
#pragma unroll
        for (int p = 0; p < 4; ++p) {
            float v0 = bflo(r0[p]), v1 = bfhi(r0[p]);
            float E0 = __expf(v0), E1 = __expf(v1);
            de[2 * p] += E0; nu[2 * p] += E0 * v0;
            de[2 * p + 1] += E1; nu[2 * p + 1] += E1 * v1;
        }
#pragma unroll
        for (int p = 0; p < 4; ++p) {
            float v0 = bflo(r1[p]), v1 = bfhi(r1[p]);
            float E0 = __expf(v0), E1 = __expf(v1);
            de[2 * p] += E0; nu[2 * p] += E0 * v0;
            de[2 * p + 1] += E1; nu[2 * p + 1] += E1 * v1;
        }
    }
    if (e < e1) {
        int s0 = srcs[e];
        u32x4 r0 = *(const u32x4*)(xb + (size_t)s0 * 512 + lane * 8);
#pragma unroll
        for (int p = 0; p < 4; ++p) {
            float v0 = bflo(r0[p]), v1 = bfhi(r0[p]);
            float E0 = __expf(v0), E1 = __expf(v1);
            de[2 * p] += E0; nu[2 * p] += E0 * v0;
            de[2 * p + 1] += E1; nu[2 * p + 1] += E1 * v1;
        }
    }
    unsigned short o[8];
#pragma unroll
    for (int j = 0; j < 8; ++j) o[j] = f2bf(nu[j] / fmaxf(de[j], 1e-16f));
    *(u32x4*)(AggBuf + (size_t)n * 512 + lane * 8) = *(const u32x4*)o;
}

// ---------------- sum aggregation (layer 2): wave-per-node ------------------
// 4 nodes/block; lane handles 4 features via one b64 load per edge.
__global__ __launch_bounds__(256) void k_agg2(const int* __restrict__ rs,
                                              const int* __restrict__ srcs,
                                              const unsigned short* __restrict__ H1,
                                              unsigned short* __restrict__ Seg) {
    int wv = threadIdx.x >> 6;
    int lane = threadIdx.x & 63;
    int n = blockIdx.x * 4 + wv;
    int e0 = rs[n], e1 = rs[n + 1];
    float a[4] = {0.f, 0.f, 0.f, 0.f};
    int e = e0;
    for (; e + 1 < e1; e += 2) {
        int s0 = srcs[e], s1 = srcs[e + 1];
        uint2 r0 = *(const uint2*)(H1 + (size_t)s0 * 256 + lane * 4);
        uint2 r1 = *(const uint2*)(H1 + (size_t)s1 * 256 + lane * 4);
        a[0] += bflo(r0.x) + bflo(r1.x);
        a[1] += bfhi(r0.x) + bfhi(r1.x);
        a[2] += bflo(r0.y) + bflo(r1.y);
        a[3] += bfhi(r0.y) + bfhi(r1.y);
    }
    if (e < e1) {
        uint2 r0 = *(const uint2*)(H1 + (size_t)srcs[e] * 256 + lane * 4);
        a[0] += bflo(r0.x); a[1] += bfhi(r0.x);
        a[2] += bflo(r0.y); a[3] += bfhi(r0.y);
    }
    uint2 o;
    o.x = (unsigned int)f2bf(a[0]) | ((unsigned int)f2bf(a[1]) << 16);
    o.y = (unsigned int)f2bf(a[2]) | ((unsigned int)f2bf(a[3]) << 16);
    *(uint2*)(Seg + (size_t)n * 256 + lane * 4) = o;
}

// ---------------- GEMM1: 64x128 tile, split-A [AggBuf|xb], -> H1 bf16 -------
// Epilogue computes the per-row index-softmax (aggidx) in-block from CSR.
__global__ __launch_bounds__(256, 5) void k_gemm1(const unsigned short* __restrict__ A1,
                                                  const unsigned short* __restrict__ A2,
                                                  const unsigned short* __restrict__ Bt,
                                                  const int* __restrict__ rs,
                                                  const int* __restrict__ srcs,
                                                  const float* __restrict__ r1,
                                                  const float* __restrict__ r2,
                                                  const float* __restrict__ bias,
                                                  unsigned short* __restrict__ outp) {
    constexpr int BM = 64, BN = 128, BK = 64;
    __shared__ __align__(16) unsigned short As[BM * BK];
    __shared__ __align__(16) unsigned short Bs[BN * BK];
    __shared__ float s1t[BM];

    const int tid = threadIdx.x;
    const int w = tid >> 6;
    const int lane = tid & 63;
    const int lm = lane & 15;
    const int quad = lane >> 4;
    const int wr = w >> 1;
    const int wc = w & 1;
    const int rowbase = blockIdx.y * BM;
    const int colbase = blockIdx.x * BN;
    const int wrow = wr * 32;
    const int wcol = wc * 64;

    const int rsub = lane >> 3;
    const int csw = (lane & 7) ^ rsub;

    f32x4 acc[2][4];
#pragma unroll
    for (int mi = 0; mi < 2; ++mi)
#pragma unroll
        for (int ni = 0; ni < 4; ++ni) acc[mi][ni] = (f32x4){0.f, 0.f, 0.f, 0.f};

    for (int kt = 0; kt < 1024; kt += BK) {
        const unsigned short* Ab = (kt < 512) ? A1 : A2;
        int kof = (kt < 512) ? kt : kt - 512;
#pragma unroll
        for (int l = 0; l < 2; ++l) {
            int r = w * 16 + l * 8;
            int gr = rowbase + r + rsub;
            if (gr >= NNODES) gr = NNODES - 1;
            const unsigned short* gp = Ab + (size_t)gr * 512 + kof + csw * 8;
            __builtin_amdgcn_global_load_lds(
                (const __attribute__((address_space(1))) void*)gp,
                (__attribute__((address_space(3))) void*)(As + r * BK), 16, 0, 0);
        }
#pragma unroll
        for (int l = 0; l < 4; ++l) {
            int r = w * 32 + l * 8;
            const unsigned short* gp = Bt + (size_t)(colbase + r + rsub) * 1024 + kt + csw * 8;
            __builtin_amdgcn_global_load_lds(
                (const __attribute__((address_space(1))) void*)gp,
                (__attribute__((address_space(3))) void*)(Bs + r * BK), 16, 0, 0);
        }
        __syncthreads();
#pragma unroll
        for (int kk = 0; kk < BK; kk += 32) {
            const int kidx = (kk >> 3) + quad;
            const int phys = kidx ^ (lm & 7);
            bf16x8 af[2], bfr[4];
#pragma unroll
            for (int mi = 0; mi < 2; ++mi)
                af[mi] = __builtin_bit_cast(bf16x8,
                    *(const u32x4*)(As + (wrow + mi * 16 + lm) * BK + phys * 8));
#pragma unroll
            for (int ni = 0; ni < 4; ++ni)
                bfr[ni] = __builtin_bit_cast(bf16x8,
                    *(const u32x4*)(Bs + (wcol + ni * 16 + lm) * BK + phys * 8));
#pragma unroll
            for (int mi = 0; mi < 2; ++mi)
#pragma unroll
                for (int ni = 0; ni < 4; ++ni)
                    acc[mi][ni] = __builtin_amdgcn_mfma_f32_16x16x32_bf16(
                        af[mi], bfr[ni], acc[mi][ni], 0, 0, 0);
        }
        __syncthreads();
    }

    // per-row index softmax (max-shifted: values up to 5e4)
    if (tid < BM) {
        int grow = rowbase + tid;
        float r_ = 0.f;
        if (grow < NNODES) {
            int e0 = rs[grow], e1 = rs[grow + 1];
            float m = -INFINITY, d = 0.f, q = 0.f;
            for (int e = e0; e < e1; ++e) {
                float v = (float)srcs[e];
                float nm = fmaxf(m, v);
                float sc = __expf(m - nm), ee = __expf(v - nm);
                d = d * sc + ee;
                q = q * sc + ee * v;
                m = nm;
            }
            r_ = q / fmaxf(d, 1e-16f);
        }
        s1t[tid] = r_;
    }
    __syncthreads();

#pragma unroll
    for (int ni = 0; ni < 4; ++ni) {
        int gc = colbase + wcol + ni * 16 + lm;
        float r1v = r1[gc], r2v = r2[gc], bv = bias[gc];
#pragma unroll
        for (int mi = 0; mi < 2; ++mi) {
#pragma unroll
            for (int r = 0; r < 4; ++r) {
                int lrow = wrow + mi * 16 + quad * 4 + r;
                int grow = rowbase + lrow;
                if (grow < NNODES) {
                    float v = acc[mi][ni][r] + s1t[lrow] * r1v + (float)grow * r2v + bv;
                    v = (v >= 0.f) ? v : 0.01f * v;
                    outp[(size_t)grow * 256 + gc] = f2bf(v);
                }
            }
        }
    }
}

// ---------------- GEMM2 + fused head: 64x64 tile, split-A [Seg|H1] ----------
__global__ __launch_bounds__(256) void k_gemm2h(const unsigned short* __restrict__ A1,
                                                const unsigned short* __restrict__ A2,
                                                const unsigned short* __restrict__ Bt,
                                                const int* __restrict__ rs,
                                                const int* __restrict__ srcs,
                                                const float* __restrict__ r1,
                                                const float* __restrict__ r2,
                                                const float* __restrict__ bias,
                                                const float* __restrict__ Wp,
                                                const float* __restrict__ bp,
                                                const float* __restrict__ Wr,
                                                const float* __restrict__ br,
                                                float* __restrict__ out) {
    constexpr int BM = 64, BN = 64, BK = 64;
    __shared__ __align__(16) unsigned short As[BM * BK];
    __shared__ __align__(16) unsigned short Bs[BN * BK];
    __shared__ float h2t[BM * 65];
    __shared__ float s1t[BM];

    const int tid = threadIdx.x;
    const int w = tid >> 6;
    const int lane = tid & 63;
    const int lm = lane & 15;
    const int quad = lane >> 4;
    const int rowbase = blockIdx.x * BM;
    const int wrow = w * 16;

    const int rsub = lane >> 3;
    const int csw = (lane & 7) ^ rsub;

    f32x4 acc[4];
#pragma unroll
    for (int ni = 0; ni < 4; ++ni) acc[ni] = (f32x4){0.f, 0.f, 0.f, 0.f};

    for (int kt = 0; kt < 512; kt += BK) {
        const unsigned short* Ab = (kt < 256) ? A1 : A2;
        int kof = (kt < 256) ? kt : kt - 256;
#pragma unroll
        for (int l = 0; l < 2; ++l) {
            int r = w * 16 + l * 8;
            int gr = rowbase + r + rsub;
            if (gr >= NNODES) gr = NNODES - 1;
            const unsigned short* gp = Ab + (size_t)gr * 256 + kof + csw * 8;
            __builtin_amdgcn_global_load_lds(
                (const __attribute__((address_space(1))) void*)gp,
                (__attribute__((address_space(3))) void*)(As + r * BK), 16, 0, 0);
        }
#pragma unroll
        for (int l = 0; l < 2; ++l) {
            int r = w * 16 + l * 8;
            const unsigned short* gp = Bt + (size_t)(r + rsub) * 512 + kt + csw * 8;
            __builtin_amdgcn_global_load_lds(
                (const __attribute__((address_space(1))) void*)gp,
                (__attribute__((address_space(3))) void*)(Bs + r * BK), 16, 0, 0);
        }
        __syncthreads();
#pragma unroll
        for (int kk = 0; kk < BK; kk += 32) {
            const int kidx = (kk >> 3) + quad;
            const int phys = kidx ^ (lm & 7);
            bf16x8 af;
            af = __builtin_bit_cast(bf16x8,
                *(const u32x4*)(As + (wrow + lm) * BK + phys * 8));
            bf16x8 bfr[4];
#pragma unroll
            for (int ni = 0; ni < 4; ++ni)
                bfr[ni] = __builtin_bit_cast(bf16x8,
                    *(const u32x4*)(Bs + (ni * 16 + lm) * BK + phys * 8));
#pragma unroll
            for (int ni = 0; ni < 4; ++ni)
                acc[ni] = __builtin_amdgcn_mfma_f32_16x16x32_bf16(
                    af, bfr[ni], acc[ni], 0, 0, 0);
        }
        __syncthreads();
    }

    // per-row index sum
    if (tid < BM) {
        int grow = rowbase + tid;
        float si = 0.f;
        if (grow < NNODES) {
            int e0 = rs[grow], e1 = rs[grow + 1];
            for (int e = e0; e < e1; ++e) si += (float)srcs[e];
        }
        s1t[tid] = si;
    }
    __syncthreads();

    // epilogue -> LDS h2 tile
#pragma unroll
    for (int ni = 0; ni < 4; ++ni) {
        int gc = ni * 16 + lm;
        float r1v = r1[gc], r2v = r2[gc], bv = bias[gc];
#pragma unroll
        for (int r = 0; r < 4; ++r) {
            int lrow = wrow + quad * 4 + r;
            int grow = rowbase + lrow;
            float v = acc[ni][r] + s1t[lrow] * r1v + (float)grow * r2v + bv;
            v = (v >= 0.f) ? v : 0.01f * v;
            h2t[lrow * 65 + gc] = v;
        }
    }
    __syncthreads();

    // head: threads 0..63, one row each
    if (tid < BM) {
        int grow = rowbase + tid;
        if (grow < NNODES) {
            const float* hv = h2t + tid * 65;
            float idx = (float)grow;
            float p0 = 0.f, p1 = 0.f, p2 = 0.f;
            float r0 = 0.f, r1a = 0.f, r2a = 0.f, r3 = 0.f;
#pragma unroll 8
            for (int c = 0; c < 64; ++c) {
                float v = hv[c];
                p0 += v * Wp[c * 3 + 0];
                p1 += v * Wp[c * 3 + 1];
                p2 += v * Wp[c * 3 + 2];
                r0 += v * Wr[c * 4 + 0];
                r1a += v * Wr[c * 4 + 1];
                r2a += v * Wr[c * 4 + 2];
                r3 += v * Wr[c * 4 + 3];
            }
            p0 += idx * Wp[64 * 3 + 0] + bp[0];
            p1 += idx * Wp[64 * 3 + 1] + bp[1];
            p2 += idx * Wp[64 * 3 + 2] + bp[2];
            r0 += idx * Wr[64 * 4 + 0] + br[0];
            r1a += idx * Wr[64 * 4 + 1] + br[1];
            r2a += idx * Wr[64 * 4 + 2] + br[2];
            r3 += idx * Wr[64 * 4 + 3] + br[3];
            float nrm = fmaxf(sqrtf(r0 * r0 + r1a * r1a + r2a * r2a + r3 * r3), 1e-12f);
            float* op = out + (size_t)grow * 7;
            op[0] = p0; op[1] = p1; op[2] = p2;
            op[3] = r0 / nrm; op[4] = r1a / nrm; op[5] = r2a / nrm; op[6] = r3 / nrm;
        }
    }
}

extern "C" void kernel_launch(void* const* d_in, const int* in_sizes, int n_in,
                              void* d_out, int out_size, void* d_ws, size_t ws_size,
                              hipStream_t stream) {
    const float* x       = (const float*)d_in[0];
    const float* W1_rel  = (const float*)d_in[1];
    const float* b1      = (const float*)d_in[2];
    const float* W1_root = (const float*)d_in[3];
    const float* W2_rel  = (const float*)d_in[4];
    const float* b2      = (const float*)d_in[5];
    const float* W2_root = (const float*)d_in[6];
    const float* Wp      = (const float*)d_in[7];
    const float* bp      = (const float*)d_in[8];
    const float* Wr      = (const float*)d_in[9];
    const float* br      = (const float*)d_in[10];
    const int*   ei      = (const int*)d_in[11];
    float* out = (float*)d_out;

    char* ws = (char*)d_ws;
    size_t off = 0;
    auto alloc = [&](size_t bytes) {
        size_t o = off;
        off = (off + bytes + 255) & ~(size_t)255;
        return (void*)(ws + o);
    };
    int*   bar       = (int*)alloc(4);
    int*   blocksum  = (int*)alloc(CSRB * 4);
    int*   deg       = (int*)alloc(NNODES * 4);
    int*   cursor    = (int*)alloc(NNODES * 4);
    int*   row_start = (int*)alloc((NNODES + 1) * 4);
    int*   srcs      = (int*)alloc(NEDGES * 4);
    unsigned short* xb     = (unsigned short*)alloc((size_t)NNODES * 512 * 2);
    unsigned short* AggBuf = (unsigned short*)alloc((size_t)NNODES * 512 * 2);
    unsigned short* H1     = (unsigned short*)alloc((size_t)NNODES * 256 * 2);
    unsigned short* Seg    = (unsigned short*)alloc((size_t)NNODES * 256 * 2);
    unsigned short* Bt1    = (unsigned short*)alloc(256 * 1024 * 2);
    unsigned short* Bt2    = (unsigned short*)alloc(64 * 512 * 2);

    hipMemsetAsync(bar, 0, 4, stream);

    k_csrprep<<<CSRB, 256, 0, stream>>>(
        x, W1_rel, W1_root, W2_rel, W2_root, ei,
        deg, row_start, cursor, srcs, Bt1, Bt2, xb, bar, blocksum);

    k_agg1<<<NNODES / 4, 256, 0, stream>>>(xb, row_start, srcs, AggBuf);

    // GEMM1: [AggBuf | xb] @ Bt1^T -> H1 (bf16, stride 256). grid (col, row)
    k_gemm1<<<dim3(2, (NNODES + 63) / 64), 256, 0, stream>>>(
        AggBuf, xb, Bt1, row_start, srcs, W1_rel + 512 * 256, W1_root + 512 * 256, b1, H1);

    k_agg2<<<NNODES / 4, 256, 0, stream>>>(row_start, srcs, H1, Seg);

    // GEMM2 + head: [Seg | H1] @ Bt2^T -> out
    k_gemm2h<<<(NNODES + 63) / 64, 256, 0, stream>>>(
        Seg, H1, Bt2, row_start, srcs, W2_rel + 256 * 64, W2_root + 256 * 64, b2,
        Wp, bp, Wr, br, out);
}

// Round 8
// 337.998 us; speedup vs baseline: 1.2384x; 1.2235x over previous
//
#include <hip/hip_runtime.h>

#define NNODES 50000
#define NEDGES 200000
#define NSCANB ((NNODES + 255) / 256)   // 196 scan blocks

typedef short  bf16x8 __attribute__((ext_vector_type(8)));
typedef float  f32x4  __attribute__((ext_vector_type(4)));
typedef unsigned int u32x4 __attribute__((ext_vector_type(4)));

__device__ __forceinline__ unsigned short f2bf(float f) {
    union { float f; unsigned int u; } c; c.f = f;
    unsigned int r = c.u + 0x7fffu + ((c.u >> 16) & 1u);
    return (unsigned short)(r >> 16);
}
__device__ __forceinline__ float bf2f(unsigned short h) {
    union { unsigned int u; float f; } c; c.u = ((unsigned int)h) << 16;
    return c.f;
}
__device__ __forceinline__ float bflo(unsigned int v) {
    union { unsigned int u; float f; } c; c.u = v << 16;
    return c.f;
}
__device__ __forceinline__ float bfhi(unsigned int v) {
    union { unsigned int u; float f; } c; c.u = v & 0xffff0000u;
    return c.f;
}

// ---------------- fused prep + edge count (wide grid-stride) ----------------
// deg[] is zeroed by hipMemsetAsync before this launch.
#define PREP_B1 (256 * 1024)
#define PREP_B2 (64 * 512)
#define PREP_XC (NNODES * 64)
__global__ __launch_bounds__(256) void k_prepcount(const float* __restrict__ x,
                                                   const float* __restrict__ W1_rel,
                                                   const float* __restrict__ W1_root,
                                                   const float* __restrict__ W2_rel,
                                                   const float* __restrict__ W2_root,
                                                   const int* __restrict__ ei,
                                                   int* __restrict__ deg,
                                                   unsigned short* __restrict__ Bt1,
                                                   unsigned short* __restrict__ Bt2,
                                                   unsigned short* __restrict__ xb) {
    const int gtid = blockIdx.x * 256 + threadIdx.x;
    const int GS = gridDim.x * 256;
    for (int e = gtid; e < NEDGES; e += GS) atomicAdd(&deg[ei[NEDGES + e]], 1);
    for (int i = gtid; i < PREP_B1; i += GS) {
        int n = i >> 10, k = i & 1023;
        float v = (k < 512) ? W1_rel[k * 256 + n] : W1_root[(k - 512) * 256 + n];
        Bt1[i] = f2bf(v);
    }
    for (int i = gtid; i < PREP_B2; i += GS) {
        int n = i >> 9, k = i & 511;
        float v = (k < 256) ? W2_rel[k * 64 + n] : W2_root[(k - 256) * 64 + n];
        Bt2[i] = f2bf(v);
    }
    for (int i = gtid; i < PREP_XC; i += GS) {
        int n = i >> 6, c8 = (i & 63) * 8;
        const float* xp = x + (size_t)n * 512 + c8;
        float4 a = *(const float4*)xp;
        float4 bb = *(const float4*)(xp + 4);
        unsigned short o[8];
        o[0] = f2bf(a.x); o[1] = f2bf(a.y); o[2] = f2bf(a.z); o[3] = f2bf(a.w);
        o[4] = f2bf(bb.x); o[5] = f2bf(bb.y); o[6] = f2bf(bb.z); o[7] = f2bf(bb.w);
        *(u32x4*)(xb + (size_t)n * 512 + c8) = *(const u32x4*)o;
    }
}

// ---------------- CSR scan: block-local exclusive ----------------
__global__ __launch_bounds__(256) void k_scanA(const int* __restrict__ deg,
                                               int* __restrict__ rs,
                                               int* __restrict__ partials) {
    __shared__ int sm[256];
    int t = threadIdx.x, i = blockIdx.x * 256 + t;
    int v = (i < NNODES) ? deg[i] : 0;
    sm[t] = v;
    __syncthreads();
#pragma unroll
    for (int off = 1; off < 256; off <<= 1) {
        int u = (t >= off) ? sm[t - off] : 0;
        __syncthreads();
        sm[t] += u;
        __syncthreads();
    }
    if (i < NNODES) rs[i] = sm[t] - v;
    if (t == 255) partials[blockIdx.x] = sm[255];
}

// fused scanB+scanC: each block reduces partials[0..b-1] itself (196 ints)
__global__ __launch_bounds__(256) void k_scanC2(int* __restrict__ rs,
                                                const int* __restrict__ partials,
                                                int* __restrict__ cursor) {
    __shared__ int sm[256];
    int t = threadIdx.x, b = blockIdx.x;
    sm[t] = (t < b && t < NSCANB) ? partials[t] : 0;
    __syncthreads();
#pragma unroll
    for (int off = 128; off; off >>= 1) {
        if (t < off) sm[t] += sm[t + off];
        __syncthreads();
    }
    int off0 = sm[0];
    int i = b * 256 + t;
    if (i < NNODES) {
        int rv = rs[i] + off0;
        rs[i] = rv;
        cursor[i] = rv;
    }
    if (i == 0) rs[NNODES] = NEDGES;
}

__global__ void k_scatter(const int* __restrict__ ei, int* __restrict__ cursor,
                          int* __restrict__ srcs) {
    int e = blockIdx.x * 256 + threadIdx.x;
    if (e < NEDGES) {
        int d = ei[NEDGES + e];
        int p = atomicAdd(&cursor[d], 1);
        srcs[p] = ei[e];
    }
}

// ---------------- softmax aggregation (layer 1): wave-per-node -------------
// 4 nodes/block; lane handles 8 features via one b128 load per edge.
// No max-subtraction: |x| < ~6, exp() safe in f32.
__global__ __launch_bounds__(256) void k_agg1(const unsigned short* __restrict__ xb,
                                              const int* __restrict__ rs,
                                              const int* __restrict__ srcs,
                                              unsigned short* __restrict__ AggBuf) {
    int wv = threadIdx.x >> 6;
    int lane = threadIdx.x & 63;
    int n = blockIdx.x * 4 + wv;
    int e0 = rs[n], e1 = rs[n + 1];
    float nu[8], de[8];
#pragma unroll
    for (int j = 0; j < 8; ++j) { nu[j] = 0.f; de[j] = 0.f; }
    int e = e0;
    for (; e + 1 < e1; e += 2) {
        int s0 = srcs[e], s1 = srcs[e + 1];
        u32x4 r0 = *(const u32x4*)(xb + (size_t)s0 * 512 + lane * 8);
        u32x4 r1 = *(const u32x4*)(xb + (size_t)s1 * 512 + lane * 8);
#pragma unroll
        for (int p = 0; p < 4; ++p) {
            float v0 = bflo(r0[p]), v1 = bfhi(r0[p]);
            float E0 = __expf(v0), E1 = __expf(v1);
            de[2 * p] += E0; nu[2 * p] += E0 * v0;
            de[2 * p + 1] += E1; nu[2 * p + 1] += E1 * v1;
        }
#pragma unroll
        for (int p = 0; p < 4; ++p) {
            float v0 = bflo(r1[p]), v1 = bfhi(r1[p]);
            float E0 = __expf(v0), E1 = __expf(v1);
            de[2 * p] += E0; nu[2 * p] += E0 * v0;
            de[2 * p + 1] += E1; nu[2 * p + 1] += E1 * v1;
        }
    }
    if (e < e1) {
        int s0 = srcs[e];
        u32x4 r0 = *(const u32x4*)(xb + (size_t)s0 * 512 + lane * 8);
#pragma unroll
        for (int p = 0; p < 4; ++p) {
            float v0 = bflo(r0[p]), v1 = bfhi(r0[p]);
            float E0 = __expf(v0), E1 = __expf(v1);
            de[2 * p] += E0; nu[2 * p] += E0 * v0;
            de[2 * p + 1] += E1; nu[2 * p + 1] += E1 * v1;
        }
    }
    unsigned short o[8];
#pragma unroll
    for (int j = 0; j < 8; ++j) o[j] = f2bf(nu[j] / fmaxf(de[j], 1e-16f));
    *(u32x4*)(AggBuf + (size_t)n * 512 + lane * 8) = *(const u32x4*)o;
}

// ---------------- sum aggregation (layer 2): wave-per-node ------------------
__global__ __launch_bounds__(256) void k_agg2(const int* __restrict__ rs,
                                              const int* __restrict__ srcs,
                                              const unsigned short* __restrict__ H1,
                                              unsigned short* __restrict__ Seg) {
    int wv = threadIdx.x >> 6;
    int lane = threadIdx.x & 63;
    int n = blockIdx.x * 4 + wv;
    int e0 = rs[n], e1 = rs[n + 1];
    float a[4] = {0.f, 0.f, 0.f, 0.f};
    int e = e0;
    for (; e + 1 < e1; e += 2) {
        int s0 = srcs[e], s1 = srcs[e + 1];
        uint2 r0 = *(const uint2*)(H1 + (size_t)s0 * 256 + lane * 4);
        uint2 r1 = *(const uint2*)(H1 + (size_t)s1 * 256 + lane * 4);
        a[0] += bflo(r0.x) + bflo(r1.x);
        a[1] += bfhi(r0.x) + bfhi(r1.x);
        a[2] += bflo(r0.y) + bflo(r1.y);
        a[3] += bfhi(r0.y) + bfhi(r1.y);
    }
    if (e < e1) {
        uint2 r0 = *(const uint2*)(H1 + (size_t)srcs[e] * 256 + lane * 4);
        a[0] += bflo(r0.x); a[1] += bfhi(r0.x);
        a[2] += bflo(r0.y); a[3] += bfhi(r0.y);
    }
    uint2 o;
    o.x = (unsigned int)f2bf(a[0]) | ((unsigned int)f2bf(a[1]) << 16);
    o.y = (unsigned int)f2bf(a[2]) | ((unsigned int)f2bf(a[3]) << 16);
    *(uint2*)(Seg + (size_t)n * 256 + lane * 4) = o;
}

// ---------------- GEMM1: 64x128 tile, split-A [AggBuf|xb], -> H1 bf16 -------
__global__ __launch_bounds__(256, 5) void k_gemm1(const unsigned short* __restrict__ A1,
                                                  const unsigned short* __restrict__ A2,
                                                  const unsigned short* __restrict__ Bt,
                                                  const int* __restrict__ rs,
                                                  const int* __restrict__ srcs,
                                                  const float* __restrict__ r1,
                                                  const float* __restrict__ r2,
                                                  const float* __restrict__ bias,
                                                  unsigned short* __restrict__ outp) {
    constexpr int BM = 64, BN = 128, BK = 64;
    __shared__ __align__(16) unsigned short As[BM * BK];
    __shared__ __align__(16) unsigned short Bs[BN * BK];
    __shared__ float s1t[BM];

    const int tid = threadIdx.x;
    const int w = tid >> 6;
    const int lane = tid & 63;
    const int lm = lane & 15;
    const int quad = lane >> 4;
    const int wr = w >> 1;
    const int wc = w & 1;
    const int rowbase = blockIdx.y * BM;
    const int colbase = blockIdx.x * BN;
    const int wrow = wr * 32;
    const int wcol = wc * 64;

    const int rsub = lane >> 3;
    const int csw = (lane & 7) ^ rsub;

    f32x4 acc[2][4];
#pragma unroll
    for (int mi = 0; mi < 2; ++mi)
#pragma unroll
        for (int ni = 0; ni < 4; ++ni) acc[mi][ni] = (f32x4){0.f, 0.f, 0.f, 0.f};

    for (int kt = 0; kt < 1024; kt += BK) {
        const unsigned short* Ab = (kt < 512) ? A1 : A2;
        int kof = (kt < 512) ? kt : kt - 512;
#pragma unroll
        for (int l = 0; l < 2; ++l) {
            int r = w * 16 + l * 8;
            int gr = rowbase + r + rsub;
            if (gr >= NNODES) gr = NNODES - 1;
            const unsigned short* gp = Ab + (size_t)gr * 512 + kof + csw * 8;
            __builtin_amdgcn_global_load_lds(
                (const __attribute__((address_space(1))) void*)gp,
                (__attribute__((address_space(3))) void*)(As + r * BK), 16, 0, 0);
        }
#pragma unroll
        for (int l = 0; l < 4; ++l) {
            int r = w * 32 + l * 8;
            const unsigned short* gp = Bt + (size_t)(colbase + r + rsub) * 1024 + kt + csw * 8;
            __builtin_amdgcn_global_load_lds(
                (const __attribute__((address_space(1))) void*)gp,
                (__attribute__((address_space(3))) void*)(Bs + r * BK), 16, 0, 0);
        }
        __syncthreads();
#pragma unroll
        for (int kk = 0; kk < BK; kk += 32) {
            const int kidx = (kk >> 3) + quad;
            const int phys = kidx ^ (lm & 7);
            bf16x8 af[2], bfr[4];
#pragma unroll
            for (int mi = 0; mi < 2; ++mi)
                af[mi] = __builtin_bit_cast(bf16x8,
                    *(const u32x4*)(As + (wrow + mi * 16 + lm) * BK + phys * 8));
#pragma unroll
            for (int ni = 0; ni < 4; ++ni)
                bfr[ni] = __builtin_bit_cast(bf16x8,
                    *(const u32x4*)(Bs + (wcol + ni * 16 + lm) * BK + phys * 8));
#pragma unroll
            for (int mi = 0; mi < 2; ++mi)
#pragma unroll
                for (int ni = 0; ni < 4; ++ni)
                    acc[mi][ni] = __builtin_amdgcn_mfma_f32_16x16x32_bf16(
                        af[mi], bfr[ni], acc[mi][ni], 0, 0, 0);
        }
        __syncthreads();
    }

    // per-row index softmax (max-shifted: values up to 5e4)
    if (tid < BM) {
        int grow = rowbase + tid;
        float r_ = 0.f;
        if (grow < NNODES) {
            int e0 = rs[grow], e1 = rs[grow + 1];
            float m = -INFINITY, d = 0.f, q = 0.f;
            for (int e = e0; e < e1; ++e) {
                float v = (float)srcs[e];
                float nm = fmaxf(m, v);
                float sc = __expf(m - nm), ee = __expf(v - nm);
                d = d * sc + ee;
                q = q * sc + ee * v;
                m = nm;
            }
            r_ = q / fmaxf(d, 1e-16f);
        }
        s1t[tid] = r_;
    }
    __syncthreads();

#pragma unroll
    for (int ni = 0; ni < 4; ++ni) {
        int gc = colbase + wcol + ni * 16 + lm;
        float r1v = r1[gc], r2v = r2[gc], bv = bias[gc];
#pragma unroll
        for (int mi = 0; mi < 2; ++mi) {
#pragma unroll
            for (int r = 0; r < 4; ++r) {
                int lrow = wrow + mi * 16 + quad * 4 + r;
                int grow = rowbase + lrow;
                if (grow < NNODES) {
                    float v = acc[mi][ni][r] + s1t[lrow] * r1v + (float)grow * r2v + bv;
                    v = (v >= 0.f) ? v : 0.01f * v;
                    outp[(size_t)grow * 256 + gc] = f2bf(v);
                }
            }
        }
    }
}

// ---------------- GEMM2 + fused head: 64x64 tile, split-A [Seg|H1] ----------
__global__ __launch_bounds__(256) void k_gemm2h(const unsigned short* __restrict__ A1,
                                                const unsigned short* __restrict__ A2,
                                                const unsigned short* __restrict__ Bt,
                                                const int* __restrict__ rs,
                                                const int* __restrict__ srcs,
                                                const float* __restrict__ r1,
                                                const float* __restrict__ r2,
                                                const float* __restrict__ bias,
                                                const float* __restrict__ Wp,
                                                const float* __restrict__ bp,
                                                const float* __restrict__ Wr,
                                                const float* __restrict__ br,
                                                float* __restrict__ out) {
    constexpr int BM = 64, BN = 64, BK = 64;
    __shared__ __align__(16) unsigned short As[BM * BK];
    __shared__ __align__(16) unsigned short Bs[BN * BK];
    __shared__ float h2t[BM * 65];
    __shared__ float s1t[BM];

    const int tid = threadIdx.x;
    const int w = tid >> 6;
    const int lane = tid & 63;
    const int lm = lane & 15;
    const int quad = lane >> 4;
    const int rowbase = blockIdx.x * BM;
    const int wrow = w * 16;

    const int rsub = lane >> 3;
    const int csw = (lane & 7) ^ rsub;

    f32x4 acc[4];
#pragma unroll
    for (int ni = 0; ni < 4; ++ni) acc[ni] = (f32x4){0.f, 0.f, 0.f, 0.f};

    for (int kt = 0; kt < 512; kt += BK) {
        const unsigned short* Ab = (kt < 256) ? A1 : A2;
        int kof = (kt < 256) ? kt : kt - 256;
#pragma unroll
        for (int l = 0; l < 2; ++l) {
            int r = w * 16 + l * 8;
            int gr = rowbase + r + rsub;
            if (gr >= NNODES) gr = NNODES - 1;
            const unsigned short* gp = Ab + (size_t)gr * 256 + kof + csw * 8;
            __builtin_amdgcn_global_load_lds(
                (const __attribute__((address_space(1))) void*)gp,
                (__attribute__((address_space(3))) void*)(As + r * BK), 16, 0, 0);
        }
#pragma unroll
        for (int l = 0; l < 2; ++l) {
            int r = w * 16 + l * 8;
            const unsigned short* gp = Bt + (size_t)(r + rsub) * 512 + kt + csw * 8;
            __builtin_amdgcn_global_load_lds(
                (const __attribute__((address_space(1))) void*)gp,
                (__attribute__((address_space(3))) void*)(Bs + r * BK), 16, 0, 0);
        }
        __syncthreads();
#pragma unroll
        for (int kk = 0; kk < BK; kk += 32) {
            const int kidx = (kk >> 3) + quad;
            const int phys = kidx ^ (lm & 7);
            bf16x8 af;
            af = __builtin_bit_cast(bf16x8,
                *(const u32x4*)(As + (wrow + lm) * BK + phys * 8));
            bf16x8 bfr[4];
#pragma unroll
            for (int ni = 0; ni < 4; ++ni)
                bfr[ni] = __builtin_bit_cast(bf16x8,
                    *(const u32x4*)(Bs + (ni * 16 + lm) * BK + phys * 8));
#pragma unroll
            for (int ni = 0; ni < 4; ++ni)
                acc[ni] = __builtin_amdgcn_mfma_f32_16x16x32_bf16(
                    af, bfr[ni], acc[ni], 0, 0, 0);
        }
        __syncthreads();
    }

    // per-row index sum
    if (tid < BM) {
        int grow = rowbase + tid;
        float si = 0.f;
        if (grow < NNODES) {
            int e0 = rs[grow], e1 = rs[grow + 1];
            for (int e = e0; e < e1; ++e) si += (float)srcs[e];
        }
        s1t[tid] = si;
    }
    __syncthreads();

    // epilogue -> LDS h2 tile
#pragma unroll
    for (int ni = 0; ni < 4; ++ni) {
        int gc = ni * 16 + lm;
        float r1v = r1[gc], r2v = r2[gc], bv = bias[gc];
#pragma unroll
        for (int r = 0; r < 4; ++r) {
            int lrow = wrow + quad * 4 + r;
            int grow = rowbase + lrow;
            float v = acc[ni][r] + s1t[lrow] * r1v + (float)grow * r2v + bv;
            v = (v >= 0.f) ? v : 0.01f * v;
            h2t[lrow * 65 + gc] = v;
        }
    }
    __syncthreads();

    // head: threads 0..63, one row each
    if (tid < BM) {
        int grow = rowbase + tid;
        if (grow < NNODES) {
            const float* hv = h2t + tid * 65;
            float idx = (float)grow;
            float p0 = 0.f, p1 = 0.f, p2 = 0.f;
            float r0 = 0.f, r1a = 0.f, r2a = 0.f, r3 = 0.f;
#pragma unroll 8
            for (int c = 0; c < 64; ++c) {
                float v = hv[c];
                p0 += v * Wp[c * 3 + 0];
                p1 += v * Wp[c * 3 + 1];
                p2 += v * Wp[c * 3 + 2];
                r0 += v * Wr[c * 4 + 0];
                r1a += v * Wr[c * 4 + 1];
                r2a += v * Wr[c * 4 + 2];
                r3 += v * Wr[c * 4 + 3];
            }
            p0 += idx * Wp[64 * 3 + 0] + bp[0];
            p1 += idx * Wp[64 * 3 + 1] + bp[1];
            p2 += idx * Wp[64 * 3 + 2] + bp[2];
            r0 += idx * Wr[64 * 4 + 0] + br[0];
            r1a += idx * Wr[64 * 4 + 1] + br[1];
            r2a += idx * Wr[64 * 4 + 2] + br[2];
            r3 += idx * Wr[64 * 4 + 3] + br[3];
            float nrm = fmaxf(sqrtf(r0 * r0 + r1a * r1a + r2a * r2a + r3 * r3), 1e-12f);
            float* op = out + (size_t)grow * 7;
            op[0] = p0; op[1] = p1; op[2] = p2;
            op[3] = r0 / nrm; op[4] = r1a / nrm; op[5] = r2a / nrm; op[6] = r3 / nrm;
        }
    }
}

extern "C" void kernel_launch(void* const* d_in, const int* in_sizes, int n_in,
                              void* d_out, int out_size, void* d_ws, size_t ws_size,
                              hipStream_t stream) {
    const float* x       = (const float*)d_in[0];
    const float* W1_rel  = (const float*)d_in[1];
    const float* b1      = (const float*)d_in[2];
    const float* W1_root = (const float*)d_in[3];
    const float* W2_rel  = (const float*)d_in[4];
    const float* b2      = (const float*)d_in[5];
    const float* W2_root = (const float*)d_in[6];
    const float* Wp      = (const float*)d_in[7];
    const float* bp      = (const float*)d_in[8];
    const float* Wr      = (const float*)d_in[9];
    const float* br      = (const float*)d_in[10];
    const int*   ei      = (const int*)d_in[11];
    float* out = (float*)d_out;

    char* ws = (char*)d_ws;
    size_t off = 0;
    auto alloc = [&](size_t bytes) {
        size_t o = off;
        off = (off + bytes + 255) & ~(size_t)255;
        return (void*)(ws + o);
    };
    int*   deg       = (int*)alloc(NNODES * 4);
    int*   cursor    = (int*)alloc(NNODES * 4);
    int*   row_start = (int*)alloc((NNODES + 1) * 4);
    int*   srcs      = (int*)alloc(NEDGES * 4);
    int*   partials  = (int*)alloc(NSCANB * 4);
    unsigned short* xb     = (unsigned short*)alloc((size_t)NNODES * 512 * 2);
    unsigned short* AggBuf = (unsigned short*)alloc((size_t)NNODES * 512 * 2);
    unsigned short* H1     = (unsigned short*)alloc((size_t)NNODES * 256 * 2);
    unsigned short* Seg    = (unsigned short*)alloc((size_t)NNODES * 256 * 2);
    unsigned short* Bt1    = (unsigned short*)alloc(256 * 1024 * 2);
    unsigned short* Bt2    = (unsigned short*)alloc(64 * 512 * 2);

    hipMemsetAsync(deg, 0, NNODES * 4, stream);

    k_prepcount<<<2048, 256, 0, stream>>>(
        x, W1_rel, W1_root, W2_rel, W2_root, ei, deg, Bt1, Bt2, xb);

    k_scanA<<<NSCANB, 256, 0, stream>>>(deg, row_start, partials);
    k_scanC2<<<NSCANB, 256, 0, stream>>>(row_start, partials, cursor);
    k_scatter<<<(NEDGES + 255) / 256, 256, 0, stream>>>(ei, cursor, srcs);

    k_agg1<<<NNODES / 4, 256, 0, stream>>>(xb, row_start, srcs, AggBuf);

    // GEMM1: [AggBuf | xb] @ Bt1^T -> H1 (bf16, stride 256). grid (col, row)
    k_gemm1<<<dim3(2, (NNODES + 63) / 64), 256, 0, stream>>>(
        AggBuf, xb, Bt1, row_start, srcs, W1_rel + 512 * 256, W1_root + 512 * 256, b1, H1);

    k_agg2<<<NNODES / 4, 256, 0, stream>>>(row_start, srcs, H1, Seg);

    // GEMM2 + head: [Seg | H1] @ Bt2^T -> out
    k_gemm2h<<<(NNODES + 63) / 64, 256, 0, stream>>>(
        Seg, H1, Bt2, row_start, srcs, W2_rel + 256 * 64, W2_root + 256 * 64, b2,
        Wp, bp, Wr, br, out);
}